// Round 7
// baseline (6384.735 us; speedup 1.0000x reference)
//
#include <hip/hip_runtime.h>

// ---------------- problem constants ----------------
#define T_STEPS 128
#define N_B     512
#define D_IN    1024
#define H_DIM   1024
#define G_DIM   3072        // 3*H
#define CHUNK   16          // timesteps per xp-GEMM chunk / persistent launch
#define NCHUNK  8
#define M_CHUNK (CHUNK * N_B)   // 8192 rows per xp-GEMM chunk
#define JC      16          // j-columns per rnn block

typedef short          s8v  __attribute__((ext_vector_type(8)));   // 8 bf16 (4 VGPR)
typedef float          f4v  __attribute__((ext_vector_type(4)));
typedef unsigned short u4v  __attribute__((ext_vector_type(4)));

__device__ __forceinline__ unsigned short f2bf(float f) {
  union { float f; unsigned u; } v; v.f = f;
  unsigned r = v.u + 0x7FFFu + ((v.u >> 16) & 1u);   // RNE
  return (unsigned short)(r >> 16);
}
__device__ __forceinline__ float bf2f(unsigned short h) {
  union { unsigned u; float f; } v; v.u = ((unsigned)h) << 16;
  return v.f;
}
__device__ __forceinline__ void async16(const void* g, void* l) {
  __builtin_amdgcn_global_load_lds(
      (const __attribute__((address_space(1))) unsigned*)g,
      (__attribute__((address_space(3))) unsigned*)l, 16, 0, 0);
}
// sc0-coherent variant: bypass vL1, read the XCD's L2 (for cross-block h state)
__device__ __forceinline__ void async16_sc0(const void* g, void* l) {
  __builtin_amdgcn_global_load_lds(
      (const __attribute__((address_space(1))) unsigned*)g,
      (__attribute__((address_space(3))) unsigned*)l, 16, 0, 1);
}
__device__ __forceinline__ float sigmoidf_(float x) { return 1.f / (1.f + __expf(-x)); }
__device__ __forceinline__ float tanhf_(float x)    { return 1.f - 2.f / (1.f + __expf(2.f * x)); }

// ---------------- f32 -> bf16 conversion (vectorized, grid-stride) ----------------
__global__ void cvt_bf16(const float* __restrict__ in, unsigned short* __restrict__ out, long n4) {
  long i = (long)blockIdx.x * blockDim.x + threadIdx.x;
  long stride = (long)gridDim.x * blockDim.x;
  for (; i < n4; i += stride) {
    f4v v = *(const f4v*)(in + i * 4);
    u4v o;
    #pragma unroll
    for (int e = 0; e < 4; ++e) o[e] = f2bf(v[e]);
    *(u4v*)(out + i * 4) = o;
  }
}

// ---------------- reset[t] = (t==0) || any(m[t,:]==1.0) ----------------
__global__ void reset_kernel(const float* __restrict__ masks, int* __restrict__ reset) {
  const int t = blockIdx.x;
  __shared__ int flag;
  if (threadIdx.x == 0) flag = (t == 0) ? 1 : 0;
  __syncthreads();
  if (t > 0 && masks[(size_t)t * N_B + threadIdx.x] == 1.0f) flag = 1;  // benign same-value race
  __syncthreads();
  if (threadIdx.x == 0) reset[t] = flag;
}

// ---------------- xp chunk GEMM: C[m][g] = sum_k A[m][k]*B[g][k] + bias[g] ----------------
__global__ __launch_bounds__(256) void gemm_xp(const unsigned short* __restrict__ A,
                                               const unsigned short* __restrict__ B,
                                               const float* __restrict__ bias,
                                               unsigned short* __restrict__ C) {
  const int m0 = blockIdx.y * 128, g0 = blockIdx.x * 128;
  const int tid = threadIdx.x, wv = tid >> 6, l = tid & 63;
  const int l15 = l & 15, l4 = l >> 4;
  const int wr = wv >> 1, wc = wv & 1;
  __shared__ unsigned short As[128 * 64], Bs[128 * 64];

  f4v zero4 = {0.f, 0.f, 0.f, 0.f};
  f4v acc[4][4];
  #pragma unroll
  for (int i = 0; i < 4; ++i)
    #pragma unroll
    for (int j = 0; j < 4; ++j) acc[i][j] = zero4;

  const int srow = l >> 3;
  const int selem = (l & 7) * 8;

  for (int kt = 0; kt < 1024; kt += 64) {
    #pragma unroll
    for (int cc = 0; cc < 4; ++cc) {
      int s = wv * 4 + cc;
      int row = s * 8 + srow;
      async16(A + (size_t)(m0 + row) * 1024 + kt + selem, &As[s * 512]);
      async16(B + (size_t)(g0 + row) * 1024 + kt + selem, &Bs[s * 512]);
    }
    __syncthreads();
    #pragma unroll
    for (int ks = 0; ks < 2; ++ks) {
      s8v a[4], b[4];
      #pragma unroll
      for (int i = 0; i < 4; ++i) {
        a[i] = *(const s8v*)&As[(wr * 64 + i * 16 + l15) * 64 + ks * 32 + l4 * 8];
        b[i] = *(const s8v*)&Bs[(wc * 64 + i * 16 + l15) * 64 + ks * 32 + l4 * 8];
      }
      #pragma unroll
      for (int i = 0; i < 4; ++i)
        #pragma unroll
        for (int j = 0; j < 4; ++j)
          acc[i][j] = __builtin_amdgcn_mfma_f32_16x16x32_bf16(a[i], b[j], acc[i][j], 0, 0, 0);
    }
    __syncthreads();
  }
  #pragma unroll
  for (int j = 0; j < 4; ++j) {
    int gcol = g0 + wc * 64 + j * 16 + l15;
    float bv = bias[gcol];
    #pragma unroll
    for (int i = 0; i < 4; ++i) {
      int mrow = m0 + wr * 64 + i * 16 + l4 * 4;
      #pragma unroll
      for (int r = 0; r < 4; ++r)
        C[(size_t)(mrow + r) * G_DIM + gcol] = f2bf(acc[i][j][r] + bv);
    }
  }
}

// ---------------- persistent GRU recurrence v3: W in registers, K-split 4 waves ----------------
// Grid 512 x 256thr, 2 blocks/CU (launch_bounds(256,2), LDS 78KB). g = bid&7 (n-group of 64
// rows, XCD-pure -> h traffic L2-local), c = bid>>3 (64 j-chunks of 16 cols).
// Wave w owns K quarter [w*256,+256): W_hh fragments preloaded ONCE per chunk (96 VGPR).
// Per step: h staged via 4-deep LDS pipeline (counted vmcnt(8) + raw s_barrier, sc0 loads),
// 12 MFMA/kt/wave; K-partials reduced in 12KB LDS (store + atomicAdd); gates on wave 0.
__global__ __launch_bounds__(256, 2) void rnn_chunk3(
    const unsigned short* __restrict__ Whh,   // [3072][1024] bf16
    const unsigned short* __restrict__ xp,    // [CHUNK][512][3072] bf16 (+b_ih)
    const float* __restrict__ masks,          // [T*N]
    const int* __restrict__ reset,            // [T]
    const float* __restrict__ bhh,            // [3072]
    const float* __restrict__ hxs,            // [512][1024] initial h (f32)
    unsigned short* hbuf,                     // [2][512][1024] bf16 state
    float* y,                                 // [T*N][1024] (d_out)
    float* hlast,                             // [512][1024]  (d_out tail)
    unsigned* bar,                            // [8] group counters (this launch's slot)
    int t0) {
  const int bid = blockIdx.x;
  const int g = bid & 7, c = bid >> 3;
  const int n0 = g * 64, j0 = c * JC;
  const int tid = threadIdx.x, w = tid >> 6, l = tid & 63;
  const int l15 = l & 15, l4 = l >> 4;
  const size_t NH = (size_t)N_B * H_DIM;

  __shared__ unsigned short Hs[4][64 * 128];  // 4 x 16 KB h pipeline (swizzled)
  __shared__ float Rs[3 * 16 * 65];           // 12.2 KB K-reduce buffer [g3][col][row pad65]

  // ---- W_hh fragments in registers, once per chunk: wave w's K quarter ----
  s8v Bf[3][8];
  #pragma unroll
  for (int g3 = 0; g3 < 3; ++g3) {
    const size_t row = (size_t)g3 * H_DIM + j0 + l15;
    #pragma unroll
    for (int ks = 0; ks < 8; ++ks)
      Bf[g3][ks] = *(const s8v*)(Whh + row * H_DIM + w * 256 + ks * 32 + l4 * 8);
  }

  // gates-phase lane constants (used by wave 0)
  const int jj = j0 + l15;
  const float br = bhh[jj];
  const float bz = bhh[H_DIM + jj];
  const float bn = bhh[2 * H_DIM + jj];

  // h_prev f32 in registers on wave 0: (rf,r) -> n = n0 + rf*16 + l4*4 + r, col jj
  float hreg[4][4];
  if (w == 0) {
    const float* hsrc = (t0 == 0) ? hxs : (y + (size_t)(t0 - 1) * NH);
    #pragma unroll
    for (int rf = 0; rf < 4; ++rf)
      #pragma unroll
      for (int r = 0; r < 4; ++r)
        hreg[rf][r] = hsrc[(size_t)(n0 + rf * 16 + l4 * 4 + r) * H_DIM + jj];
  }

  const int srow = l >> 4;          // staging row-within-4
  const int sslot = l & 15;         // staging 16B slot

  f4v zero4 = {0.f, 0.f, 0.f, 0.f};
  s8v zer8 = {0, 0, 0, 0, 0, 0, 0, 0};

  for (int ls = 0; ls < CHUNK; ++ls) {
    const int t = t0 + ls;
    const unsigned short* hread = hbuf + (size_t)(t & 1) * NH;
    unsigned short* hwrite = hbuf + (size_t)((t & 1) ^ 1) * NH;
    const int rst = reset[t];

    bool zo[4];
    #pragma unroll
    for (int rf = 0; rf < 4; ++rf) {
      float mv = masks[(size_t)t * N_B + n0 + rf * 16 + l15];
      zo[rf] = rst && (mv == 0.0f);
    }

    f4v acc[4][3];
    #pragma unroll
    for (int rf = 0; rf < 4; ++rf)
      #pragma unroll
      for (int g3 = 0; g3 < 3; ++g3) acc[rf][g3] = zero4;

    // stage one 16KB kt-slab: cols = 4 K-quarters x 32; pre-swizzled source, linear dest
    auto stageH = [&](int kt) {
      #pragma unroll
      for (int q = 0; q < 4; ++q) {
        const int s = w * 4 + q;
        const int row = s * 4 + srow;                       // 0..63
        const int sw = sslot ^ (row & 7);                   // swizzled 16B slot
        const int k = (sw >> 2) * 256 + kt * 32 + (sw & 3) * 8;
        async16_sc0(hread + (size_t)(n0 + row) * H_DIM + k, &Hs[kt & 3][s * 4 * 128]);
      }
    };

    stageH(0); stageH(1); stageH(2);            // 12 outstanding per wave

    #pragma unroll
    for (int kt = 0; kt < 8; ++kt) {
      if (kt < 6)      asm volatile("s_waitcnt vmcnt(8)" ::: "memory");
      else if (kt == 6) asm volatile("s_waitcnt vmcnt(4)" ::: "memory");
      else              asm volatile("s_waitcnt vmcnt(0)" ::: "memory");
      __builtin_amdgcn_s_barrier();
      __builtin_amdgcn_sched_barrier(0);
      if (kt + 3 < 8) stageH(kt + 3);           // prefetch stays in flight across barriers
      const char* hb = (const char*)&Hs[kt & 3][0];
      s8v a[4];
      #pragma unroll
      for (int rf = 0; rf < 4; ++rf) {
        const int rr = rf * 16 + l15;
        const int byo = (w * 64 + l4 * 16) ^ ((rr & 7) << 4);
        a[rf] = *(const s8v*)(hb + rr * 256 + byo);
        if (zo[rf]) a[rf] = zer8;
      }
      #pragma unroll
      for (int rf = 0; rf < 4; ++rf)
        #pragma unroll
        for (int g3 = 0; g3 < 3; ++g3)
          acc[rf][g3] = __builtin_amdgcn_mfma_f32_16x16x32_bf16(a[rf], Bf[g3][kt], acc[rf][g3], 0, 0, 0);
    }

    // ---- K-reduce in LDS: w1 stores, w2+w3 atomicAdd, w0 reads+adds own ----
    __syncthreads();
    if (w == 1) {
      #pragma unroll
      for (int g3 = 0; g3 < 3; ++g3)
        #pragma unroll
        for (int rf = 0; rf < 4; ++rf)
          #pragma unroll
          for (int r = 0; r < 4; ++r)
            Rs[(g3 * 16 + l15) * 65 + rf * 16 + l4 * 4 + r] = acc[rf][g3][r];
    }
    __syncthreads();
    if (w >= 2) {
      #pragma unroll
      for (int g3 = 0; g3 < 3; ++g3)
        #pragma unroll
        for (int rf = 0; rf < 4; ++rf)
          #pragma unroll
          for (int r = 0; r < 4; ++r)
            atomicAdd(&Rs[(g3 * 16 + l15) * 65 + rf * 16 + l4 * 4 + r], acc[rf][g3][r]);
    }
    __syncthreads();

    // ---- gates on wave 0 ----
    if (w == 0) {
      const unsigned short* xpt = xp + (size_t)ls * N_B * G_DIM;
      #pragma unroll
      for (int rf = 0; rf < 4; ++rf) {
        #pragma unroll
        for (int r = 0; r < 4; ++r) {
          const int n = n0 + rf * 16 + l4 * 4 + r;
          const float m = masks[(size_t)t * N_B + n];
          float hprev = hreg[rf][r];
          if (rst && m == 0.0f) hprev = 0.0f;
          const int ri = l15 * 65 + rf * 16 + l4 * 4 + r;
          const float hr = acc[rf][0][r] + Rs[(0 * 16) * 65 + ri] + br;
          const float hz = acc[rf][1][r] + Rs[(16) * 65 + ri] + bz;
          const float hn = acc[rf][2][r] + Rs[(32) * 65 + ri] + bn;
          const size_t xo = (size_t)n * G_DIM + jj;
          const float xr = bf2f(xpt[xo]);
          const float xz = bf2f(xpt[xo + H_DIM]);
          const float xn = bf2f(xpt[xo + 2 * H_DIM]);
          const float rg = sigmoidf_(xr + hr);
          const float zg = sigmoidf_(xz + hz);
          const float ng = tanhf_(xn + rg * hn);
          const float hnew = (1.f - zg) * ng + zg * hprev;
          hreg[rf][r] = hnew;
          const size_t gidx = (size_t)n * H_DIM + jj;
          y[(size_t)t * NH + gidx] = hnew;
          hwrite[gidx] = f2bf(hnew);
          if (t == T_STEPS - 1) hlast[gidx] = hnew;
        }
      }
    }

    // ---- group barrier (64 blocks, same XCD), relaxed atomics, no cache inval ----
    __syncthreads();                            // drains wave0's h stores (vmcnt) pre-arrival
    if (tid == 0) {
      __hip_atomic_fetch_add(&bar[g], 1u, __ATOMIC_RELAXED, __HIP_MEMORY_SCOPE_AGENT);
      const unsigned tgt = 64u * (unsigned)(ls + 1);
      while (__hip_atomic_load(&bar[g], __ATOMIC_RELAXED, __HIP_MEMORY_SCOPE_AGENT) < tgt)
        __builtin_amdgcn_s_sleep(2);
    }
    __syncthreads();
  }
}

// ---------------- final LayerNorm over y rows (in place) ----------------
__global__ __launch_bounds__(256) void ln_kernel(float* __restrict__ y,
                                                 const float* __restrict__ gamma,
                                                 const float* __restrict__ beta) {
  const size_t row = blockIdx.x;
  float* p = y + row * (size_t)H_DIM;
  const int tid = threadIdx.x;
  f4v v = *(const f4v*)(p + tid * 4);
  float s = v[0] + v[1] + v[2] + v[3];
  float q = v[0] * v[0] + v[1] * v[1] + v[2] * v[2] + v[3] * v[3];
  #pragma unroll
  for (int off = 32; off > 0; off >>= 1) {
    s += __shfl_down(s, off);
    q += __shfl_down(q, off);
  }
  __shared__ float sb[8];
  const int wid = tid >> 6, lid = tid & 63;
  if (lid == 0) { sb[wid] = s; sb[4 + wid] = q; }
  __syncthreads();
  float S = sb[0] + sb[1] + sb[2] + sb[3];
  float Q = sb[4] + sb[5] + sb[6] + sb[7];
  float mean = S * (1.f / H_DIM);
  float var = Q * (1.f / H_DIM) - mean * mean;
  float inv = rsqrtf(var + 1e-5f);
  f4v g4 = *(const f4v*)(gamma + tid * 4);
  f4v b4 = *(const f4v*)(beta + tid * 4);
  f4v o;
  #pragma unroll
  for (int e = 0; e < 4; ++e) o[e] = (v[e] - mean) * inv * g4[e] + b4[e];
  *(f4v*)(p + tid * 4) = o;
}

// ---------------- host ----------------
extern "C" void kernel_launch(void* const* d_in, const int* in_sizes, int n_in,
                              void* d_out, int out_size, void* d_ws, size_t ws_size,
                              hipStream_t stream) {
  const float* x     = (const float*)d_in[0];
  const float* hxs   = (const float*)d_in[1];
  const float* masks = (const float*)d_in[2];
  const float* W_ih  = (const float*)d_in[3];
  const float* W_hh  = (const float*)d_in[4];
  const float* b_ih  = (const float*)d_in[5];
  const float* b_hh  = (const float*)d_in[6];
  const float* gamma = (const float*)d_in[7];
  const float* beta  = (const float*)d_in[8];
  float* y = (float*)d_out;                                 // [65536][1024]
  float* hlast = y + (size_t)T_STEPS * N_B * H_DIM;         // [512][1024]

  char* ws = (char*)d_ws;
  unsigned short* Wih_bf = (unsigned short*)ws;  ws += (size_t)G_DIM * D_IN * 2;       // 6.3 MB
  unsigned short* Whh_bf = (unsigned short*)ws;  ws += (size_t)G_DIM * H_DIM * 2;      // 6.3 MB
  unsigned short* xc_bf  = (unsigned short*)ws;  ws += (size_t)M_CHUNK * D_IN * 2;     // 16.8 MB
  unsigned short* xp_bf  = (unsigned short*)ws;  ws += (size_t)M_CHUNK * G_DIM * 2;    // 50.3 MB
  unsigned short* hbuf   = (unsigned short*)ws;  ws += (size_t)2 * N_B * H_DIM * 2;    // 2.1 MB
  int* reset             = (int*)ws;             ws += 512;
  unsigned* bars         = (unsigned*)ws;        ws += NCHUNK * 8 * sizeof(unsigned);

  hipMemsetAsync(bars, 0, NCHUNK * 8 * sizeof(unsigned), stream);
  cvt_bf16<<<1024, 256, 0, stream>>>(W_ih, Wih_bf, (long)G_DIM * D_IN / 4);
  cvt_bf16<<<1024, 256, 0, stream>>>(W_hh, Whh_bf, (long)G_DIM * H_DIM / 4);
  cvt_bf16<<<512, 256, 0, stream>>>(hxs, hbuf, (long)N_B * H_DIM / 4);   // hbuf[0] = bf16(h0)
  reset_kernel<<<128, 512, 0, stream>>>(masks, reset);

  for (int ck = 0; ck < NCHUNK; ++ck) {
    const float* xck = x + (size_t)ck * M_CHUNK * D_IN;
    cvt_bf16<<<2048, 256, 0, stream>>>(xck, xc_bf, (long)M_CHUNK * D_IN / 4);
    dim3 gg(G_DIM / 128, M_CHUNK / 128);   // (24, 64)
    gemm_xp<<<gg, 256, 0, stream>>>(xc_bf, Wih_bf, b_ih, xp_bf);

    rnn_chunk3<<<512, 256, 0, stream>>>(Whh_bf, xp_bf, masks, reset, b_hh,
                                        hxs, hbuf, y, hlast, bars + ck * 8, ck * CHUNK);
  }

  ln_kernel<<<T_STEPS * N_B, 256, 0, stream>>>(y, gamma, beta);
}

// Round 8
// 3466.064 us; speedup vs baseline: 1.8421x; 1.8421x over previous
//
#include <hip/hip_runtime.h>

// ---------------- problem constants ----------------
#define T_STEPS 128
#define N_B     512
#define D_IN    1024
#define H_DIM   1024
#define G_DIM   3072        // 3*H
#define CHUNK   16          // timesteps per xp-GEMM chunk / persistent launch
#define NCHUNK  8
#define M_CHUNK (CHUNK * N_B)   // 8192 rows per xp-GEMM chunk

typedef short          s8v  __attribute__((ext_vector_type(8)));   // 8 bf16 (4 VGPR)
typedef float          f4v  __attribute__((ext_vector_type(4)));
typedef unsigned short u4v  __attribute__((ext_vector_type(4)));

__device__ __forceinline__ unsigned short f2bf(float f) {
  union { float f; unsigned u; } v; v.f = f;
  unsigned r = v.u + 0x7FFFu + ((v.u >> 16) & 1u);   // RNE
  return (unsigned short)(r >> 16);
}
__device__ __forceinline__ float bf2f(unsigned short h) {
  union { unsigned u; float f; } v; v.u = ((unsigned)h) << 16;
  return v.f;
}
__device__ __forceinline__ void async16(const void* g, void* l) {
  __builtin_amdgcn_global_load_lds(
      (const __attribute__((address_space(1))) unsigned*)g,
      (__attribute__((address_space(3))) unsigned*)l, 16, 0, 0);
}
// sc0|sc1 coherent load: bypass L1+L2, read from the shared Infinity Cache (cross-XCD h)
__device__ __forceinline__ void async16_coh(const void* g, void* l) {
  __builtin_amdgcn_global_load_lds(
      (const __attribute__((address_space(1))) unsigned*)g,
      (__attribute__((address_space(3))) unsigned*)l, 16, 0, 17);
}
// sc0|sc1 coherent bf16 store: write through L2 to the coherence point (cross-XCD h)
__device__ __forceinline__ void store_bf16_coh(unsigned short* p, unsigned short v) {
  unsigned v32 = v;
  asm volatile("global_store_short %0, %1, off sc0 sc1" :: "v"(p), "v"(v32) : "memory");
}
__device__ __forceinline__ float sigmoidf_(float x) { return 1.f / (1.f + __expf(-x)); }
__device__ __forceinline__ float tanhf_(float x)    { return 1.f - 2.f / (1.f + __expf(2.f * x)); }

// ---------------- f32 -> bf16 conversion (vectorized, grid-stride) ----------------
__global__ void cvt_bf16(const float* __restrict__ in, unsigned short* __restrict__ out, long n4) {
  long i = (long)blockIdx.x * blockDim.x + threadIdx.x;
  long stride = (long)gridDim.x * blockDim.x;
  for (; i < n4; i += stride) {
    f4v v = *(const f4v*)(in + i * 4);
    u4v o;
    #pragma unroll
    for (int e = 0; e < 4; ++e) o[e] = f2bf(v[e]);
    *(u4v*)(out + i * 4) = o;
  }
}

// ---------------- reset[t] = (t==0) || any(m[t,:]==1.0) ----------------
__global__ void reset_kernel(const float* __restrict__ masks, int* __restrict__ reset) {
  const int t = blockIdx.x;
  __shared__ int flag;
  if (threadIdx.x == 0) flag = (t == 0) ? 1 : 0;
  __syncthreads();
  if (t > 0 && masks[(size_t)t * N_B + threadIdx.x] == 1.0f) flag = 1;  // benign same-value race
  __syncthreads();
  if (threadIdx.x == 0) reset[t] = flag;
}

// ---------------- xp chunk GEMM: C[m][g] = sum_k A[m][k]*B[g][k] + bias[g] ----------------
__global__ __launch_bounds__(256) void gemm_xp(const unsigned short* __restrict__ A,
                                               const unsigned short* __restrict__ B,
                                               const float* __restrict__ bias,
                                               unsigned short* __restrict__ C) {
  const int m0 = blockIdx.y * 128, g0 = blockIdx.x * 128;
  const int tid = threadIdx.x, wv = tid >> 6, l = tid & 63;
  const int l15 = l & 15, l4 = l >> 4;
  const int wr = wv >> 1, wc = wv & 1;
  __shared__ unsigned short As[128 * 64], Bs[128 * 64];

  f4v zero4 = {0.f, 0.f, 0.f, 0.f};
  f4v acc[4][4];
  #pragma unroll
  for (int i = 0; i < 4; ++i)
    #pragma unroll
    for (int j = 0; j < 4; ++j) acc[i][j] = zero4;

  const int srow = l >> 3;
  const int selem = (l & 7) * 8;

  for (int kt = 0; kt < 1024; kt += 64) {
    #pragma unroll
    for (int cc = 0; cc < 4; ++cc) {
      int s = wv * 4 + cc;
      int row = s * 8 + srow;
      async16(A + (size_t)(m0 + row) * 1024 + kt + selem, &As[s * 512]);
      async16(B + (size_t)(g0 + row) * 1024 + kt + selem, &Bs[s * 512]);
    }
    __syncthreads();
    #pragma unroll
    for (int ks = 0; ks < 2; ++ks) {
      s8v a[4], b[4];
      #pragma unroll
      for (int i = 0; i < 4; ++i) {
        a[i] = *(const s8v*)&As[(wr * 64 + i * 16 + l15) * 64 + ks * 32 + l4 * 8];
        b[i] = *(const s8v*)&Bs[(wc * 64 + i * 16 + l15) * 64 + ks * 32 + l4 * 8];
      }
      #pragma unroll
      for (int i = 0; i < 4; ++i)
        #pragma unroll
        for (int j = 0; j < 4; ++j)
          acc[i][j] = __builtin_amdgcn_mfma_f32_16x16x32_bf16(a[i], b[j], acc[i][j], 0, 0, 0);
    }
    __syncthreads();
  }
  #pragma unroll
  for (int j = 0; j < 4; ++j) {
    int gcol = g0 + wc * 64 + j * 16 + l15;
    float bv = bias[gcol];
    #pragma unroll
    for (int i = 0; i < 4; ++i) {
      int mrow = m0 + wr * 64 + i * 16 + l4 * 4;
      #pragma unroll
      for (int r = 0; r < 4; ++r)
        C[(size_t)(mrow + r) * G_DIM + gcol] = f2bf(acc[i][j][r] + bv);
    }
  }
}

// ---------------- persistent GRU recurrence v4: j-major XCD map + L3 h-exchange ----------------
// Grid 256 blocks (1/CU, co-resident): jt = bid&31 (j0=jt*32), nt = bid>>5 (n0=nt*64).
//   XCD = bid%8 = jt%8 -> each XCD serves 4 jt slices: W footprint 4x192KB = 768KB, L2-RESIDENT
//   across all 16 steps (R3-proven mapping; R6's n-major thrashed W through a 4MB L2).
// h-exchange: block (jt,nt) needs h rows of its own nt-group only -> barrier scope = 32 blocks
//   sharing nt (8 parallel counters, R6-proven). Those span XCDs, so h crosses via the shared
//   L3: h-writes sc0|sc1 (write-through), h-stage reads sc0|sc1 (bypass stale L1/L2). No fences.
// Core: R6-proven dbuf LDS staging (BK=128, 80KB), gates fully in-register, h f32 in regs.
__global__ __launch_bounds__(256) void rnn_chunk4(
    const unsigned short* __restrict__ Whh,   // [3072][1024] bf16
    const unsigned short* __restrict__ xp,    // [CHUNK][512][3072] bf16 (+b_ih)
    const float* __restrict__ masks,          // [T*N]
    const int* __restrict__ reset,            // [T]
    const float* __restrict__ bhh,            // [3072]
    const float* __restrict__ hxs,            // [512][1024] initial h (f32)
    unsigned short* hbuf,                     // [2][512][1024] bf16 state
    float* y,                                 // [T*N][1024] (d_out)
    float* hlast,                             // [512][1024]  (d_out tail)
    unsigned* bar,                            // [8] nt-group counters (this launch's slot)
    int t0) {
  const int bid = blockIdx.x;
  const int jt = bid & 31, nt = bid >> 5;
  const int j0 = jt * 32, n0 = nt * 64;
  const int tid = threadIdx.x, w = tid >> 6, l = tid & 63;
  const int l15 = l & 15, l4 = l >> 4;
  const int wn = w & 1, wj = w >> 1;          // wave -> (n-half of 32, j-half of 16)
  const size_t NH = (size_t)N_B * H_DIM;

  __shared__ unsigned short Hs[2][64 * 128];  // 2 x 16 KB (h slab, swizzled)
  __shared__ unsigned short Ws[2][96 * 128];  // 2 x 24 KB (W slab, swizzled)

  const int lrow4 = l >> 4;                   // staging: lane -> row-within-4
  const int lcb = (l & 15) * 16;              // staging: lane -> 16B col slot
  const int swz_rd = (l15 & 7) << 4;          // read-side row-XOR

  const int jj = j0 + wj * 16 + l15;
  const float br = bhh[jj];
  const float bz = bhh[H_DIM + jj];
  const float bn = bhh[2 * H_DIM + jj];

  // h_prev f32 in registers, layout == acc layout: (i,r) -> n = n0+wn*32+i*16+l4*4+r
  float hreg[2][4];
  {
    const float* hsrc = (t0 == 0) ? hxs : (y + (size_t)(t0 - 1) * NH);
    #pragma unroll
    for (int i = 0; i < 2; ++i)
      #pragma unroll
      for (int r = 0; r < 4; ++r)
        hreg[i][r] = hsrc[(size_t)(n0 + wn * 32 + i * 16 + l4 * 4 + r) * H_DIM + jj];
  }

  f4v zero4 = {0.f, 0.f, 0.f, 0.f};
  s8v zer8 = {0, 0, 0, 0, 0, 0, 0, 0};

  for (int ls = 0; ls < CHUNK; ++ls) {
    const int t = t0 + ls;
    const unsigned short* hread = hbuf + (size_t)(t & 1) * NH;
    unsigned short* hwrite = hbuf + (size_t)((t & 1) ^ 1) * NH;
    const int rst = reset[t];

    bool zo[2];
    #pragma unroll
    for (int i = 0; i < 2; ++i) {
      float mv = masks[(size_t)t * N_B + n0 + wn * 32 + i * 16 + l15];
      zo[i] = rst && (mv == 0.0f);
    }

    f4v acc[2][3];
    #pragma unroll
    for (int i = 0; i < 2; ++i)
      #pragma unroll
      for (int g3 = 0; g3 < 3; ++g3) acc[i][g3] = zero4;

    // ---- staging (wave-uniform LDS dest, per-lane pre-swizzled global src) ----
    auto stageH = [&](int buf, int kt) {
      #pragma unroll
      for (int q = 0; q < 4; ++q) {
        int rb = w * 16 + q * 4;
        int row = rb + lrow4;                                   // 0..63
        int cb = lcb ^ ((row & 7) << 4);                        // byte in 256B row
        async16_coh(hread + (size_t)(n0 + row) * H_DIM + kt * 128 + (cb >> 1),
                    &Hs[buf][rb * 128]);                        // sc0|sc1: fresh from L3
      }
    };
    auto stageW = [&](int buf, int kt) {
      #pragma unroll
      for (int q = 0; q < 6; ++q) {
        int rb = w * 24 + q * 4;
        int row = rb + lrow4;                                   // 0..95
        int gate = row >> 5, jjl = row & 31;
        int cb = lcb ^ ((row & 7) << 4);
        async16(Whh + ((size_t)gate * H_DIM + j0 + jjl) * H_DIM + kt * 128 + (cb >> 1),
                &Ws[buf][rb * 128]);                            // normal: L2-resident per XCD
      }
    };

    stageH(0, 0);
    stageW(0, 0);
    __syncthreads();

    for (int kt = 0; kt < 8; ++kt) {
      const int cur = kt & 1;
      if (kt < 7) { stageH(cur ^ 1, kt + 1); stageW(cur ^ 1, kt + 1); }  // prefetch under MFMA
      const char* hb = (const char*)&Hs[cur][0];
      const char* wb = (const char*)&Ws[cur][0];
      #pragma unroll
      for (int ks = 0; ks < 4; ++ks) {
        const int kbb = (ks * 64 + l4 * 16) ^ swz_rd;
        s8v a[2], b[3];
        #pragma unroll
        for (int i = 0; i < 2; ++i) {
          a[i] = *(const s8v*)(hb + (wn * 32 + i * 16 + l15) * 256 + kbb);
          if (zo[i]) a[i] = zer8;
        }
        #pragma unroll
        for (int g3 = 0; g3 < 3; ++g3)
          b[g3] = *(const s8v*)(wb + (g3 * 32 + wj * 16 + l15) * 256 + kbb);
        #pragma unroll
        for (int i = 0; i < 2; ++i)
          #pragma unroll
          for (int g3 = 0; g3 < 3; ++g3)
            acc[i][g3] = __builtin_amdgcn_mfma_f32_16x16x32_bf16(a[i], b[g3], acc[i][g3], 0, 0, 0);
      }
      __syncthreads();
    }

    // ---- gates fully in-register ----
    const unsigned short* xpt = xp + (size_t)ls * N_B * G_DIM;
    #pragma unroll
    for (int i = 0; i < 2; ++i) {
      #pragma unroll
      for (int r = 0; r < 4; ++r) {
        const int n = n0 + wn * 32 + i * 16 + l4 * 4 + r;
        const float m = masks[(size_t)t * N_B + n];
        float hprev = hreg[i][r];
        if (rst && m == 0.0f) hprev = 0.0f;
        const float hr = acc[i][0][r] + br;
        const float hz = acc[i][1][r] + bz;
        const float hn = acc[i][2][r] + bn;
        const size_t xo = (size_t)n * G_DIM + jj;
        const float xr = bf2f(xpt[xo]);
        const float xz = bf2f(xpt[xo + H_DIM]);
        const float xn = bf2f(xpt[xo + 2 * H_DIM]);
        const float rg = sigmoidf_(xr + hr);
        const float zg = sigmoidf_(xz + hz);
        const float ng = tanhf_(xn + rg * hn);
        const float hnew = (1.f - zg) * ng + zg * hprev;
        hreg[i][r] = hnew;
        const size_t gidx = (size_t)n * H_DIM + jj;
        y[(size_t)t * NH + gidx] = hnew;
        store_bf16_coh(hwrite + gidx, f2bf(hnew));   // through L2 -> visible cross-XCD
        if (t == T_STEPS - 1) hlast[gidx] = hnew;
      }
    }

    // ---- nt-group barrier (32 blocks, cross-XCD), relaxed atomics, no cache inval ----
    // __syncthreads drains vmcnt(0) -> all sc1 h-stores have reached the coherence point
    // before tid0's increment; readers re-fetch h with sc0|sc1 loads next step.
    __syncthreads();
    if (tid == 0) {
      __hip_atomic_fetch_add(&bar[nt], 1u, __ATOMIC_RELAXED, __HIP_MEMORY_SCOPE_AGENT);
      const unsigned tgt = 32u * (unsigned)(ls + 1);
      while (__hip_atomic_load(&bar[nt], __ATOMIC_RELAXED, __HIP_MEMORY_SCOPE_AGENT) < tgt)
        __builtin_amdgcn_s_sleep(2);
    }
    __syncthreads();
  }
}

// ---------------- final LayerNorm over y rows (in place) ----------------
__global__ __launch_bounds__(256) void ln_kernel(float* __restrict__ y,
                                                 const float* __restrict__ gamma,
                                                 const float* __restrict__ beta) {
  const size_t row = blockIdx.x;
  float* p = y + row * (size_t)H_DIM;
  const int tid = threadIdx.x;
  f4v v = *(const f4v*)(p + tid * 4);
  float s = v[0] + v[1] + v[2] + v[3];
  float q = v[0] * v[0] + v[1] * v[1] + v[2] * v[2] + v[3] * v[3];
  #pragma unroll
  for (int off = 32; off > 0; off >>= 1) {
    s += __shfl_down(s, off);
    q += __shfl_down(q, off);
  }
  __shared__ float sb[8];
  const int wid = tid >> 6, lid = tid & 63;
  if (lid == 0) { sb[wid] = s; sb[4 + wid] = q; }
  __syncthreads();
  float S = sb[0] + sb[1] + sb[2] + sb[3];
  float Q = sb[4] + sb[5] + sb[6] + sb[7];
  float mean = S * (1.f / H_DIM);
  float var = Q * (1.f / H_DIM) - mean * mean;
  float inv = rsqrtf(var + 1e-5f);
  f4v g4 = *(const f4v*)(gamma + tid * 4);
  f4v b4 = *(const f4v*)(beta + tid * 4);
  f4v o;
  #pragma unroll
  for (int e = 0; e < 4; ++e) o[e] = (v[e] - mean) * inv * g4[e] + b4[e];
  *(f4v*)(p + tid * 4) = o;
}

// ---------------- host ----------------
extern "C" void kernel_launch(void* const* d_in, const int* in_sizes, int n_in,
                              void* d_out, int out_size, void* d_ws, size_t ws_size,
                              hipStream_t stream) {
  const float* x     = (const float*)d_in[0];
  const float* hxs   = (const float*)d_in[1];
  const float* masks = (const float*)d_in[2];
  const float* W_ih  = (const float*)d_in[3];
  const float* W_hh  = (const float*)d_in[4];
  const float* b_ih  = (const float*)d_in[5];
  const float* b_hh  = (const float*)d_in[6];
  const float* gamma = (const float*)d_in[7];
  const float* beta  = (const float*)d_in[8];
  float* y = (float*)d_out;                                 // [65536][1024]
  float* hlast = y + (size_t)T_STEPS * N_B * H_DIM;         // [512][1024]

  char* ws = (char*)d_ws;
  unsigned short* Wih_bf = (unsigned short*)ws;  ws += (size_t)G_DIM * D_IN * 2;       // 6.3 MB
  unsigned short* Whh_bf = (unsigned short*)ws;  ws += (size_t)G_DIM * H_DIM * 2;      // 6.3 MB
  unsigned short* xc_bf  = (unsigned short*)ws;  ws += (size_t)M_CHUNK * D_IN * 2;     // 16.8 MB
  unsigned short* xp_bf  = (unsigned short*)ws;  ws += (size_t)M_CHUNK * G_DIM * 2;    // 50.3 MB
  unsigned short* hbuf   = (unsigned short*)ws;  ws += (size_t)2 * N_B * H_DIM * 2;    // 2.1 MB
  int* reset             = (int*)ws;             ws += 512;
  unsigned* bars         = (unsigned*)ws;        ws += NCHUNK * 8 * sizeof(unsigned);

  hipMemsetAsync(bars, 0, NCHUNK * 8 * sizeof(unsigned), stream);
  cvt_bf16<<<1024, 256, 0, stream>>>(W_ih, Wih_bf, (long)G_DIM * D_IN / 4);
  cvt_bf16<<<1024, 256, 0, stream>>>(W_hh, Whh_bf, (long)G_DIM * H_DIM / 4);
  cvt_bf16<<<512, 256, 0, stream>>>(hxs, hbuf, (long)N_B * H_DIM / 4);   // hbuf[0] = bf16(h0)
  reset_kernel<<<128, 512, 0, stream>>>(masks, reset);

  for (int ck = 0; ck < NCHUNK; ++ck) {
    const float* xck = x + (size_t)ck * M_CHUNK * D_IN;
    cvt_bf16<<<2048, 256, 0, stream>>>(xck, xc_bf, (long)M_CHUNK * D_IN / 4);
    dim3 gg(G_DIM / 128, M_CHUNK / 128);   // (24, 64)
    gemm_xp<<<gg, 256, 0, stream>>>(xc_bf, Wih_bf, b_ih, xp_bf);

    rnn_chunk4<<<256, 256, 0, stream>>>(Whh_bf, xp_bf, masks, reset, b_hh,
                                        hxs, hbuf, y, hlast, bars + ck * 8, ck * CHUNK);
  }

  ln_kernel<<<T_STEPS * N_B, 256, 0, stream>>>(y, gamma, beta);
}

// Round 9
// 2915.822 us; speedup vs baseline: 2.1897x; 1.1887x over previous
//
#include <hip/hip_runtime.h>

// ---------------- problem constants ----------------
#define T_STEPS 128
#define N_B     512
#define D_IN    1024
#define H_DIM   1024
#define G_DIM   3072        // 3*H
#define CHUNK   16          // timesteps per xp-GEMM chunk / persistent launch
#define NCHUNK  8
#define M_CHUNK (CHUNK * N_B)   // 8192 rows per xp-GEMM chunk

typedef short          s8v  __attribute__((ext_vector_type(8)));   // 8 bf16 (4 VGPR)
typedef float          f4v  __attribute__((ext_vector_type(4)));
typedef unsigned short u4v  __attribute__((ext_vector_type(4)));

__device__ __forceinline__ unsigned short f2bf(float f) {
  union { float f; unsigned u; } v; v.f = f;
  unsigned r = v.u + 0x7FFFu + ((v.u >> 16) & 1u);   // RNE
  return (unsigned short)(r >> 16);
}
__device__ __forceinline__ float bf2f(unsigned short h) {
  union { unsigned u; float f; } v; v.u = ((unsigned)h) << 16;
  return v.f;
}
__device__ __forceinline__ void async16(const void* g, void* l) {
  __builtin_amdgcn_global_load_lds(
      (const __attribute__((address_space(1))) unsigned*)g,
      (__attribute__((address_space(3))) unsigned*)l, 16, 0, 0);
}
// sc0|sc1 coherent load: bypass L1+L2, read from the shared Infinity Cache (cross-XCD h)
__device__ __forceinline__ void async16_coh(const void* g, void* l) {
  __builtin_amdgcn_global_load_lds(
      (const __attribute__((address_space(1))) unsigned*)g,
      (__attribute__((address_space(3))) unsigned*)l, 16, 0, 17);
}
// sc0|sc1 coherent bf16 store: write through L2 to the coherence point (cross-XCD h)
__device__ __forceinline__ void store_bf16_coh(unsigned short* p, unsigned short v) {
  unsigned v32 = v;
  asm volatile("global_store_short %0, %1, off sc0 sc1" :: "v"(p), "v"(v32) : "memory");
}
__device__ __forceinline__ float sigmoidf_(float x) { return 1.f / (1.f + __expf(-x)); }
__device__ __forceinline__ float tanhf_(float x)    { return 1.f - 2.f / (1.f + __expf(2.f * x)); }

// ---------------- f32 -> bf16 conversion (vectorized, grid-stride) ----------------
__global__ void cvt_bf16(const float* __restrict__ in, unsigned short* __restrict__ out, long n4) {
  long i = (long)blockIdx.x * blockDim.x + threadIdx.x;
  long stride = (long)gridDim.x * blockDim.x;
  for (; i < n4; i += stride) {
    f4v v = *(const f4v*)(in + i * 4);
    u4v o;
    #pragma unroll
    for (int e = 0; e < 4; ++e) o[e] = f2bf(v[e]);
    *(u4v*)(out + i * 4) = o;
  }
}

// ---------------- reset[t] = (t==0) || any(m[t,:]==1.0) ----------------
__global__ void reset_kernel(const float* __restrict__ masks, int* __restrict__ reset) {
  const int t = blockIdx.x;
  __shared__ int flag;
  if (threadIdx.x == 0) flag = (t == 0) ? 1 : 0;
  __syncthreads();
  if (t > 0 && masks[(size_t)t * N_B + threadIdx.x] == 1.0f) flag = 1;  // benign same-value race
  __syncthreads();
  if (threadIdx.x == 0) reset[t] = flag;
}

// ---------------- xp chunk GEMM: C[m][g] = sum_k A[m][k]*B[g][k] + bias[g] ----------------
__global__ __launch_bounds__(256) void gemm_xp(const unsigned short* __restrict__ A,
                                               const unsigned short* __restrict__ B,
                                               const float* __restrict__ bias,
                                               unsigned short* __restrict__ C) {
  const int m0 = blockIdx.y * 128, g0 = blockIdx.x * 128;
  const int tid = threadIdx.x, wv = tid >> 6, l = tid & 63;
  const int l15 = l & 15, l4 = l >> 4;
  const int wr = wv >> 1, wc = wv & 1;
  __shared__ unsigned short As[128 * 64], Bs[128 * 64];

  f4v zero4 = {0.f, 0.f, 0.f, 0.f};
  f4v acc[4][4];
  #pragma unroll
  for (int i = 0; i < 4; ++i)
    #pragma unroll
    for (int j = 0; j < 4; ++j) acc[i][j] = zero4;

  const int srow = l >> 3;
  const int selem = (l & 7) * 8;

  for (int kt = 0; kt < 1024; kt += 64) {
    #pragma unroll
    for (int cc = 0; cc < 4; ++cc) {
      int s = wv * 4 + cc;
      int row = s * 8 + srow;
      async16(A + (size_t)(m0 + row) * 1024 + kt + selem, &As[s * 512]);
      async16(B + (size_t)(g0 + row) * 1024 + kt + selem, &Bs[s * 512]);
    }
    __syncthreads();
    #pragma unroll
    for (int ks = 0; ks < 2; ++ks) {
      s8v a[4], b[4];
      #pragma unroll
      for (int i = 0; i < 4; ++i) {
        a[i] = *(const s8v*)&As[(wr * 64 + i * 16 + l15) * 64 + ks * 32 + l4 * 8];
        b[i] = *(const s8v*)&Bs[(wc * 64 + i * 16 + l15) * 64 + ks * 32 + l4 * 8];
      }
      #pragma unroll
      for (int i = 0; i < 4; ++i)
        #pragma unroll
        for (int j = 0; j < 4; ++j)
          acc[i][j] = __builtin_amdgcn_mfma_f32_16x16x32_bf16(a[i], b[j], acc[i][j], 0, 0, 0);
    }
    __syncthreads();
  }
  #pragma unroll
  for (int j = 0; j < 4; ++j) {
    int gcol = g0 + wc * 64 + j * 16 + l15;
    float bv = bias[gcol];
    #pragma unroll
    for (int i = 0; i < 4; ++i) {
      int mrow = m0 + wr * 64 + i * 16 + l4 * 4;
      #pragma unroll
      for (int r = 0; r < 4; ++r)
        C[(size_t)(mrow + r) * G_DIM + gcol] = f2bf(acc[i][j][r] + bv);
    }
  }
}

// ---------------- persistent GRU recurrence v5: v4 + counted-vmcnt pipeline (T3/T4) ----------------
// Grid 256 (1/CU): jt = bid&31 (j0=jt*32), nt = bid>>5 (n0=nt*64). XCD = jt%8 -> W L2-resident.
// h cross-XCD via L3 (sc0|sc1 loads/stores, v8-proven). NEW vs v4:
//  - 3-buffer LDS rotation; per-kt raw s_barrier with s_waitcnt vmcnt(10) (NOT a full drain):
//    stage(kt+1) stays in flight across the barrier; stage(kt+2) issued AFTER the barrier
//    (so all waves have finished reading buf[(kt+2)%3] == buf[(kt-1)%3] before it's overwritten).
//  - xp/mask prefetched into VGPRs before stage(0): oldest VMEM, absorbed by kt0's vmcnt wait;
//    gates run with zero load latency.
__global__ __launch_bounds__(256) void rnn_chunk5(
    const unsigned short* __restrict__ Whh,   // [3072][1024] bf16
    const unsigned short* __restrict__ xp,    // [CHUNK][512][3072] bf16 (+b_ih)
    const float* __restrict__ masks,          // [T*N]
    const int* __restrict__ reset,            // [T]
    const float* __restrict__ bhh,            // [3072]
    const float* __restrict__ hxs,            // [512][1024] initial h (f32)
    unsigned short* hbuf,                     // [2][512][1024] bf16 state
    float* y,                                 // [T*N][1024] (d_out)
    float* hlast,                             // [512][1024]  (d_out tail)
    unsigned* bar,                            // [8] nt-group counters (this launch's slot)
    int t0) {
  const int bid = blockIdx.x;
  const int jt = bid & 31, nt = bid >> 5;
  const int j0 = jt * 32, n0 = nt * 64;
  const int tid = threadIdx.x, w = tid >> 6, l = tid & 63;
  const int l15 = l & 15, l4 = l >> 4;
  const int wn = w & 1, wj = w >> 1;          // wave -> (n-half of 32, j-half of 16)
  const size_t NH = (size_t)N_B * H_DIM;

  __shared__ unsigned short Hs[3][64 * 128];  // 3 x 16 KB (h slab, swizzled)
  __shared__ unsigned short Ws[3][96 * 128];  // 3 x 24 KB (W slab, swizzled)

  const int lrow4 = l >> 4;                   // staging: lane -> row-within-4
  const int lcb = (l & 15) * 16;              // staging: lane -> 16B col slot
  const int swz_rd = (l15 & 7) << 4;          // read-side row-XOR

  const int jj = j0 + wj * 16 + l15;
  const float br = bhh[jj];
  const float bz = bhh[H_DIM + jj];
  const float bn = bhh[2 * H_DIM + jj];

  // h_prev f32 in registers, layout == acc layout: (i,r) -> n = n0+wn*32+i*16+l4*4+r
  float hreg[2][4];
  {
    const float* hsrc = (t0 == 0) ? hxs : (y + (size_t)(t0 - 1) * NH);
    #pragma unroll
    for (int i = 0; i < 2; ++i)
      #pragma unroll
      for (int r = 0; r < 4; ++r)
        hreg[i][r] = hsrc[(size_t)(n0 + wn * 32 + i * 16 + l4 * 4 + r) * H_DIM + jj];
  }

  f4v zero4 = {0.f, 0.f, 0.f, 0.f};
  s8v zer8 = {0, 0, 0, 0, 0, 0, 0, 0};

  for (int ls = 0; ls < CHUNK; ++ls) {
    const int t = t0 + ls;
    const unsigned short* hread = hbuf + (size_t)(t & 1) * NH;
    unsigned short* hwrite = hbuf + (size_t)((t & 1) ^ 1) * NH;
    const int rst = reset[t];
    const unsigned short* xpt = xp + (size_t)ls * N_B * G_DIM;

    // ---- prefetch: masks (zo + gate m) and xp into VGPRs (oldest VMEM this step) ----
    bool zo[2];
    #pragma unroll
    for (int i = 0; i < 2; ++i) {
      float mv = masks[(size_t)t * N_B + n0 + wn * 32 + i * 16 + l15];
      zo[i] = rst && (mv == 0.0f);
    }
    float mreg[2][4];
    unsigned short xpr[2][4][3];
    #pragma unroll
    for (int i = 0; i < 2; ++i)
      #pragma unroll
      for (int r = 0; r < 4; ++r) {
        const int n = n0 + wn * 32 + i * 16 + l4 * 4 + r;
        mreg[i][r] = masks[(size_t)t * N_B + n];
        const size_t xo = (size_t)n * G_DIM + jj;
        #pragma unroll
        for (int g3 = 0; g3 < 3; ++g3)
          xpr[i][r][g3] = xpt[xo + (size_t)g3 * H_DIM];
      }

    f4v acc[2][3];
    #pragma unroll
    for (int i = 0; i < 2; ++i)
      #pragma unroll
      for (int g3 = 0; g3 < 3; ++g3) acc[i][g3] = zero4;

    // ---- staging (wave-uniform LDS dest, per-lane pre-swizzled global src): 10 VMEM/wave ----
    auto stage = [&](int buf, int kt) {
      #pragma unroll
      for (int q = 0; q < 4; ++q) {
        int rb = w * 16 + q * 4;
        int row = rb + lrow4;                                   // 0..63
        int cb = lcb ^ ((row & 7) << 4);                        // byte in 256B row
        async16_coh(hread + (size_t)(n0 + row) * H_DIM + kt * 128 + (cb >> 1),
                    &Hs[buf][rb * 128]);                        // sc0|sc1: fresh via L3
      }
      #pragma unroll
      for (int q = 0; q < 6; ++q) {
        int rb = w * 24 + q * 4;
        int row = rb + lrow4;                                   // 0..95
        int gate = row >> 5, jjl = row & 31;
        int cb = lcb ^ ((row & 7) << 4);
        async16(Whh + ((size_t)gate * H_DIM + j0 + jjl) * H_DIM + kt * 128 + (cb >> 1),
                &Ws[buf][rb * 128]);                            // normal: L2-resident per XCD
      }
    };

    stage(0, 0);
    stage(1, 1);

    // ---- kt pipeline: counted vmcnt + raw s_barrier; stage issue AFTER barrier ----
    #pragma unroll
    for (int kt = 0; kt < 8; ++kt) {
      if (kt < 7) asm volatile("s_waitcnt vmcnt(10)" ::: "memory");  // buf[kt]'s 10 done;
      else        asm volatile("s_waitcnt vmcnt(0)"  ::: "memory");  // buf[kt+1] in flight
      __builtin_amdgcn_s_barrier();
      __builtin_amdgcn_sched_barrier(0);
      if (kt < 6) stage((kt + 2) % 3, kt + 2);   // safe: all waves past barrier -> kt-1 reads done
      const char* hb = (const char*)&Hs[kt % 3][0];
      const char* wb = (const char*)&Ws[kt % 3][0];
      #pragma unroll
      for (int ks = 0; ks < 4; ++ks) {
        const int kbb = (ks * 64 + l4 * 16) ^ swz_rd;
        s8v a[2], b[3];
        #pragma unroll
        for (int i = 0; i < 2; ++i) {
          a[i] = *(const s8v*)(hb + (wn * 32 + i * 16 + l15) * 256 + kbb);
          if (zo[i]) a[i] = zer8;
        }
        #pragma unroll
        for (int g3 = 0; g3 < 3; ++g3)
          b[g3] = *(const s8v*)(wb + (g3 * 32 + wj * 16 + l15) * 256 + kbb);
        #pragma unroll
        for (int i = 0; i < 2; ++i)
          #pragma unroll
          for (int g3 = 0; g3 < 3; ++g3)
            acc[i][g3] = __builtin_amdgcn_mfma_f32_16x16x32_bf16(a[i], b[g3], acc[i][g3], 0, 0, 0);
      }
    }

    // ---- gates fully in-register (xp/m prefetched -> no load latency) ----
    #pragma unroll
    for (int i = 0; i < 2; ++i) {
      #pragma unroll
      for (int r = 0; r < 4; ++r) {
        const int n = n0 + wn * 32 + i * 16 + l4 * 4 + r;
        float hprev = hreg[i][r];
        if (rst && mreg[i][r] == 0.0f) hprev = 0.0f;
        const float hr = acc[i][0][r] + br;
        const float hz = acc[i][1][r] + bz;
        const float hn = acc[i][2][r] + bn;
        const float xr = bf2f(xpr[i][r][0]);
        const float xz = bf2f(xpr[i][r][1]);
        const float xn = bf2f(xpr[i][r][2]);
        const float rg = sigmoidf_(xr + hr);
        const float zg = sigmoidf_(xz + hz);
        const float ng = tanhf_(xn + rg * hn);
        const float hnew = (1.f - zg) * ng + zg * hprev;
        hreg[i][r] = hnew;
        const size_t gidx = (size_t)n * H_DIM + jj;
        y[(size_t)t * NH + gidx] = hnew;
        store_bf16_coh(hwrite + gidx, f2bf(hnew));   // through L2 -> visible cross-XCD
        if (t == T_STEPS - 1) hlast[gidx] = hnew;
      }
    }

    // ---- nt-group barrier (32 blocks, cross-XCD), relaxed atomics, no cache inval ----
    __syncthreads();                            // full drain: h stores at coherence point
    if (tid == 0) {
      __hip_atomic_fetch_add(&bar[nt], 1u, __ATOMIC_RELAXED, __HIP_MEMORY_SCOPE_AGENT);
      const unsigned tgt = 32u * (unsigned)(ls + 1);
      while (__hip_atomic_load(&bar[nt], __ATOMIC_RELAXED, __HIP_MEMORY_SCOPE_AGENT) < tgt)
        __builtin_amdgcn_s_sleep(2);
    }
    __syncthreads();
  }
}

// ---------------- final LayerNorm over y rows (in place) ----------------
__global__ __launch_bounds__(256) void ln_kernel(float* __restrict__ y,
                                                 const float* __restrict__ gamma,
                                                 const float* __restrict__ beta) {
  const size_t row = blockIdx.x;
  float* p = y + row * (size_t)H_DIM;
  const int tid = threadIdx.x;
  f4v v = *(const f4v*)(p + tid * 4);
  float s = v[0] + v[1] + v[2] + v[3];
  float q = v[0] * v[0] + v[1] * v[1] + v[2] * v[2] + v[3] * v[3];
  #pragma unroll
  for (int off = 32; off > 0; off >>= 1) {
    s += __shfl_down(s, off);
    q += __shfl_down(q, off);
  }
  __shared__ float sb[8];
  const int wid = tid >> 6, lid = tid & 63;
  if (lid == 0) { sb[wid] = s; sb[4 + wid] = q; }
  __syncthreads();
  float S = sb[0] + sb[1] + sb[2] + sb[3];
  float Q = sb[4] + sb[5] + sb[6] + sb[7];
  float mean = S * (1.f / H_DIM);
  float var = Q * (1.f / H_DIM) - mean * mean;
  float inv = rsqrtf(var + 1e-5f);
  f4v g4 = *(const f4v*)(gamma + tid * 4);
  f4v b4 = *(const f4v*)(beta + tid * 4);
  f4v o;
  #pragma unroll
  for (int e = 0; e < 4; ++e) o[e] = (v[e] - mean) * inv * g4[e] + b4[e];
  *(f4v*)(p + tid * 4) = o;
}

// ---------------- host ----------------
extern "C" void kernel_launch(void* const* d_in, const int* in_sizes, int n_in,
                              void* d_out, int out_size, void* d_ws, size_t ws_size,
                              hipStream_t stream) {
  const float* x     = (const float*)d_in[0];
  const float* hxs   = (const float*)d_in[1];
  const float* masks = (const float*)d_in[2];
  const float* W_ih  = (const float*)d_in[3];
  const float* W_hh  = (const float*)d_in[4];
  const float* b_ih  = (const float*)d_in[5];
  const float* b_hh  = (const float*)d_in[6];
  const float* gamma = (const float*)d_in[7];
  const float* beta  = (const float*)d_in[8];
  float* y = (float*)d_out;                                 // [65536][1024]
  float* hlast = y + (size_t)T_STEPS * N_B * H_DIM;         // [512][1024]

  char* ws = (char*)d_ws;
  unsigned short* Wih_bf = (unsigned short*)ws;  ws += (size_t)G_DIM * D_IN * 2;       // 6.3 MB
  unsigned short* Whh_bf = (unsigned short*)ws;  ws += (size_t)G_DIM * H_DIM * 2;      // 6.3 MB
  unsigned short* xc_bf  = (unsigned short*)ws;  ws += (size_t)M_CHUNK * D_IN * 2;     // 16.8 MB
  unsigned short* xp_bf  = (unsigned short*)ws;  ws += (size_t)M_CHUNK * G_DIM * 2;    // 50.3 MB
  unsigned short* hbuf   = (unsigned short*)ws;  ws += (size_t)2 * N_B * H_DIM * 2;    // 2.1 MB
  int* reset             = (int*)ws;             ws += 512;
  unsigned* bars         = (unsigned*)ws;        ws += NCHUNK * 8 * sizeof(unsigned);

  hipMemsetAsync(bars, 0, NCHUNK * 8 * sizeof(unsigned), stream);
  cvt_bf16<<<1024, 256, 0, stream>>>(W_ih, Wih_bf, (long)G_DIM * D_IN / 4);
  cvt_bf16<<<1024, 256, 0, stream>>>(W_hh, Whh_bf, (long)G_DIM * H_DIM / 4);
  cvt_bf16<<<512, 256, 0, stream>>>(hxs, hbuf, (long)N_B * H_DIM / 4);   // hbuf[0] = bf16(h0)
  reset_kernel<<<128, 512, 0, stream>>>(masks, reset);

  for (int ck = 0; ck < NCHUNK; ++ck) {
    const float* xck = x + (size_t)ck * M_CHUNK * D_IN;
    cvt_bf16<<<2048, 256, 0, stream>>>(xck, xc_bf, (long)M_CHUNK * D_IN / 4);
    dim3 gg(G_DIM / 128, M_CHUNK / 128);   // (24, 64)
    gemm_xp<<<gg, 256, 0, stream>>>(xc_bf, Wih_bf, b_ih, xp_bf);

    rnn_chunk5<<<256, 256, 0, stream>>>(Whh_bf, xp_bf, masks, reset, b_hh,
                                        hxs, hbuf, y, hlast, bars + ck * 8, ck * CHUNK);
  }

  ln_kernel<<<T_STEPS * N_B, 256, 0, stream>>>(y, gamma, beta);
}

// Round 10
// 2577.251 us; speedup vs baseline: 2.4773x; 1.1314x over previous
//
#include <hip/hip_runtime.h>

// ---------------- problem constants ----------------
#define T_STEPS 128
#define N_B     512
#define D_IN    1024
#define H_DIM   1024
#define G_DIM   3072        // 3*H
#define M_ALL   (T_STEPS * N_B)   // 65536 rows

typedef short          s8v  __attribute__((ext_vector_type(8)));   // 8 bf16 (4 VGPR)
typedef float          f4v  __attribute__((ext_vector_type(4)));
typedef unsigned short u4v  __attribute__((ext_vector_type(4)));

__device__ __forceinline__ unsigned short f2bf(float f) {
  union { float f; unsigned u; } v; v.f = f;
  unsigned r = v.u + 0x7FFFu + ((v.u >> 16) & 1u);   // RNE
  return (unsigned short)(r >> 16);
}
__device__ __forceinline__ float bf2f(unsigned short h) {
  union { unsigned u; float f; } v; v.u = ((unsigned)h) << 16;
  return v.f;
}
__device__ __forceinline__ void async16(const void* g, void* l) {
  __builtin_amdgcn_global_load_lds(
      (const __attribute__((address_space(1))) unsigned*)g,
      (__attribute__((address_space(3))) unsigned*)l, 16, 0, 0);
}
__device__ __forceinline__ float sigmoidf_(float x) { return 1.f / (1.f + __expf(-x)); }
__device__ __forceinline__ float tanhf_(float x)    { return 1.f - 2.f / (1.f + __expf(2.f * x)); }

// ---------------- f32 -> bf16 conversion (vectorized, grid-stride) ----------------
__global__ void cvt_bf16(const float* __restrict__ in, unsigned short* __restrict__ out, long n4) {
  long i = (long)blockIdx.x * blockDim.x + threadIdx.x;
  long stride = (long)gridDim.x * blockDim.x;
  for (; i < n4; i += stride) {
    f4v v = *(const f4v*)(in + i * 4);
    u4v o;
    #pragma unroll
    for (int e = 0; e < 4; ++e) o[e] = f2bf(v[e]);
    *(u4v*)(out + i * 4) = o;
  }
}

// ---------------- reset[t] = (t==0) || any(m[t,:]==1.0) ----------------
__global__ void reset_kernel(const float* __restrict__ masks, int* __restrict__ reset) {
  const int t = blockIdx.x;
  __shared__ int flag;
  if (threadIdx.x == 0) flag = (t == 0) ? 1 : 0;
  __syncthreads();
  if (t > 0 && masks[(size_t)t * N_B + threadIdx.x] == 1.0f) flag = 1;  // benign same-value race
  __syncthreads();
  if (threadIdx.x == 0) reset[t] = flag;
}

// ---------------- xp GEMM (ALL timesteps): C[m][g] = sum_k A[m][k]*B[g][k] + bias[g] ----------------
__global__ __launch_bounds__(256) void gemm_xp(const unsigned short* __restrict__ A,
                                               const unsigned short* __restrict__ B,
                                               const float* __restrict__ bias,
                                               unsigned short* __restrict__ C) {
  const int m0 = blockIdx.y * 128, g0 = blockIdx.x * 128;
  const int tid = threadIdx.x, wv = tid >> 6, l = tid & 63;
  const int l15 = l & 15, l4 = l >> 4;
  const int wr = wv >> 1, wc = wv & 1;
  __shared__ unsigned short As[128 * 64], Bs[128 * 64];

  f4v zero4 = {0.f, 0.f, 0.f, 0.f};
  f4v acc[4][4];
  #pragma unroll
  for (int i = 0; i < 4; ++i)
    #pragma unroll
    for (int j = 0; j < 4; ++j) acc[i][j] = zero4;

  const int srow = l >> 3;
  const int selem = (l & 7) * 8;

  for (int kt = 0; kt < 1024; kt += 64) {
    #pragma unroll
    for (int cc = 0; cc < 4; ++cc) {
      int s = wv * 4 + cc;
      int row = s * 8 + srow;
      async16(A + (size_t)(m0 + row) * 1024 + kt + selem, &As[s * 512]);
      async16(B + (size_t)(g0 + row) * 1024 + kt + selem, &Bs[s * 512]);
    }
    __syncthreads();
    #pragma unroll
    for (int ks = 0; ks < 2; ++ks) {
      s8v a[4], b[4];
      #pragma unroll
      for (int i = 0; i < 4; ++i) {
        a[i] = *(const s8v*)&As[(wr * 64 + i * 16 + l15) * 64 + ks * 32 + l4 * 8];
        b[i] = *(const s8v*)&Bs[(wc * 64 + i * 16 + l15) * 64 + ks * 32 + l4 * 8];
      }
      #pragma unroll
      for (int i = 0; i < 4; ++i)
        #pragma unroll
        for (int j = 0; j < 4; ++j)
          acc[i][j] = __builtin_amdgcn_mfma_f32_16x16x32_bf16(a[i], b[j], acc[i][j], 0, 0, 0);
    }
    __syncthreads();
  }
  #pragma unroll
  for (int j = 0; j < 4; ++j) {
    int gcol = g0 + wc * 64 + j * 16 + l15;
    float bv = bias[gcol];
    #pragma unroll
    for (int i = 0; i < 4; ++i) {
      int mrow = m0 + wr * 64 + i * 16 + l4 * 4;
      #pragma unroll
      for (int r = 0; r < 4; ++r)
        C[(size_t)(mrow + r) * G_DIM + gcol] = f2bf(acc[i][j][r] + bv);
    }
  }
}

// ---------------- one GRU timestep, v6: per-step launch + counted-vmcnt pipeline ----------------
// Lesson R9: kernel boundary (~2us) beats software cross-XCD coherence (~14us/step). Grid 256
// (1/CU): jt = bid&31 (j0=jt*32), nt = bid>>5 (n0=nt*64). XCD = jt%8 -> W slice 768KB/XCD stays
// L2-resident ACROSS launches (L2 is writeback, not flushed at kernel boundary).
// Core (R9-proven): VGPR-prefetch h_prev/masks/xp first (oldest VMEM), 3-buffer LDS rotation,
// per-kt raw s_barrier with counted vmcnt(10) -> next-slab loads stay in flight across barriers;
// stage(kt+2) issued after barrier kt (all waves done reading that buffer). Gates in-register.
__global__ __launch_bounds__(256) void gru_step6(
    const unsigned short* __restrict__ Whh,   // [3072][1024] bf16
    const unsigned short* __restrict__ xp,    // [T*512][3072] bf16 (+b_ih)
    const float* __restrict__ masks,          // [T*N]
    const int* __restrict__ reset,            // [T]
    const float* __restrict__ bhh,            // [3072]
    const float* __restrict__ hxs,            // [512][1024] initial h (f32)
    const unsigned short* __restrict__ hread, // bf16 h_prev [512][1024]
    unsigned short* __restrict__ hwrite,      // bf16 h_new  [512][1024]
    float* __restrict__ y,                    // [T*N][1024]
    float* __restrict__ hlast,                // [512][1024]
    int t) {
  const int bid = blockIdx.x;
  const int jt = bid & 31, nt = bid >> 5;
  const int j0 = jt * 32, n0 = nt * 64;
  const int tid = threadIdx.x, w = tid >> 6, l = tid & 63;
  const int l15 = l & 15, l4 = l >> 4;
  const int wn = w & 1, wj = w >> 1;          // wave -> (n-half of 32, j-half of 16)
  const size_t NH = (size_t)N_B * H_DIM;

  __shared__ unsigned short Hs[3][64 * 128];  // 3 x 16 KB (h slab, swizzled)
  __shared__ unsigned short Ws[3][96 * 128];  // 3 x 24 KB (W slab, swizzled)

  const int lrow4 = l >> 4;                   // staging: lane -> row-within-4
  const int lcb = (l & 15) * 16;              // staging: lane -> 16B col slot
  const int swz_rd = (l15 & 7) << 4;          // read-side row-XOR

  const int jj = j0 + wj * 16 + l15;
  const int rst = reset[t];
  const unsigned short* xpt = xp + (size_t)t * N_B * G_DIM;

  // ---- prefetch into VGPRs FIRST (oldest VMEM -> absorbed by kt0's vmcnt wait) ----
  bool zo[2];
  #pragma unroll
  for (int i = 0; i < 2; ++i) {
    float mv = masks[(size_t)t * N_B + n0 + wn * 32 + i * 16 + l15];
    zo[i] = rst && (mv == 0.0f);
  }
  const float* hsrc = (t == 0) ? hxs : (y + (size_t)(t - 1) * NH);
  float hreg[2][4], mreg[2][4];
  unsigned short xpr[2][4][3];
  #pragma unroll
  for (int i = 0; i < 2; ++i)
    #pragma unroll
    for (int r = 0; r < 4; ++r) {
      const int n = n0 + wn * 32 + i * 16 + l4 * 4 + r;
      hreg[i][r] = hsrc[(size_t)n * H_DIM + jj];
      mreg[i][r] = masks[(size_t)t * N_B + n];
      const size_t xo = (size_t)n * G_DIM + jj;
      #pragma unroll
      for (int g3 = 0; g3 < 3; ++g3)
        xpr[i][r][g3] = xpt[xo + (size_t)g3 * H_DIM];
    }
  const float br = bhh[jj];
  const float bz = bhh[H_DIM + jj];
  const float bn = bhh[2 * H_DIM + jj];

  f4v zero4 = {0.f, 0.f, 0.f, 0.f};
  s8v zer8 = {0, 0, 0, 0, 0, 0, 0, 0};
  f4v acc[2][3];
  #pragma unroll
  for (int i = 0; i < 2; ++i)
    #pragma unroll
    for (int g3 = 0; g3 < 3; ++g3) acc[i][g3] = zero4;

  // ---- staging (wave-uniform LDS dest, per-lane pre-swizzled global src): 10 VMEM/wave ----
  auto stage = [&](int buf, int kt) {
    #pragma unroll
    for (int q = 0; q < 4; ++q) {
      int rb = w * 16 + q * 4;
      int row = rb + lrow4;                                   // 0..63
      int cb = lcb ^ ((row & 7) << 4);                        // byte in 256B row
      async16(hread + (size_t)(n0 + row) * H_DIM + kt * 128 + (cb >> 1), &Hs[buf][rb * 128]);
    }
    #pragma unroll
    for (int q = 0; q < 6; ++q) {
      int rb = w * 24 + q * 4;
      int row = rb + lrow4;                                   // 0..95
      int gate = row >> 5, jjl = row & 31;
      int cb = lcb ^ ((row & 7) << 4);
      async16(Whh + ((size_t)gate * H_DIM + j0 + jjl) * H_DIM + kt * 128 + (cb >> 1),
              &Ws[buf][rb * 128]);                            // L2-resident per XCD
    }
  };

  stage(0, 0);
  stage(1, 1);

  // ---- kt pipeline: counted vmcnt + raw s_barrier; stage issue AFTER barrier ----
  #pragma unroll
  for (int kt = 0; kt < 8; ++kt) {
    if (kt < 7) asm volatile("s_waitcnt vmcnt(10)" ::: "memory");  // buf[kt] done; buf[kt+1] in flight
    else        asm volatile("s_waitcnt vmcnt(0)"  ::: "memory");
    __builtin_amdgcn_s_barrier();
    __builtin_amdgcn_sched_barrier(0);
    if (kt < 6) stage((kt + 2) % 3, kt + 2);   // safe: all waves past barrier -> kt-1 reads done
    const char* hb = (const char*)&Hs[kt % 3][0];
    const char* wb = (const char*)&Ws[kt % 3][0];
    #pragma unroll
    for (int ks = 0; ks < 4; ++ks) {
      const int kbb = (ks * 64 + l4 * 16) ^ swz_rd;
      s8v a[2], b[3];
      #pragma unroll
      for (int i = 0; i < 2; ++i) {
        a[i] = *(const s8v*)(hb + (wn * 32 + i * 16 + l15) * 256 + kbb);
        if (zo[i]) a[i] = zer8;
      }
      #pragma unroll
      for (int g3 = 0; g3 < 3; ++g3)
        b[g3] = *(const s8v*)(wb + (g3 * 32 + wj * 16 + l15) * 256 + kbb);
      #pragma unroll
      for (int i = 0; i < 2; ++i)
        #pragma unroll
        for (int g3 = 0; g3 < 3; ++g3)
          acc[i][g3] = __builtin_amdgcn_mfma_f32_16x16x32_bf16(a[i], b[g3], acc[i][g3], 0, 0, 0);
    }
  }

  // ---- gates fully in-register (all inputs prefetched -> no load latency) ----
  #pragma unroll
  for (int i = 0; i < 2; ++i) {
    #pragma unroll
    for (int r = 0; r < 4; ++r) {
      const int n = n0 + wn * 32 + i * 16 + l4 * 4 + r;
      float hprev = hreg[i][r];
      if (rst && mreg[i][r] == 0.0f) hprev = 0.0f;
      const float hr = acc[i][0][r] + br;
      const float hz = acc[i][1][r] + bz;
      const float hn = acc[i][2][r] + bn;
      const float xr = bf2f(xpr[i][r][0]);
      const float xz = bf2f(xpr[i][r][1]);
      const float xn = bf2f(xpr[i][r][2]);
      const float rg = sigmoidf_(xr + hr);
      const float zg = sigmoidf_(xz + hz);
      const float ng = tanhf_(xn + rg * hn);
      const float hnew = (1.f - zg) * ng + zg * hprev;
      const size_t gidx = (size_t)n * H_DIM + jj;
      y[(size_t)t * NH + gidx] = hnew;
      hwrite[gidx] = f2bf(hnew);
      if (t == T_STEPS - 1) hlast[gidx] = hnew;
    }
  }
}

// ---------------- final LayerNorm over y rows (in place) ----------------
__global__ __launch_bounds__(256) void ln_kernel(float* __restrict__ y,
                                                 const float* __restrict__ gamma,
                                                 const float* __restrict__ beta) {
  const size_t row = blockIdx.x;
  float* p = y + row * (size_t)H_DIM;
  const int tid = threadIdx.x;
  f4v v = *(const f4v*)(p + tid * 4);
  float s = v[0] + v[1] + v[2] + v[3];
  float q = v[0] * v[0] + v[1] * v[1] + v[2] * v[2] + v[3] * v[3];
  #pragma unroll
  for (int off = 32; off > 0; off >>= 1) {
    s += __shfl_down(s, off);
    q += __shfl_down(q, off);
  }
  __shared__ float sb[8];
  const int wid = tid >> 6, lid = tid & 63;
  if (lid == 0) { sb[wid] = s; sb[4 + wid] = q; }
  __syncthreads();
  float S = sb[0] + sb[1] + sb[2] + sb[3];
  float Q = sb[4] + sb[5] + sb[6] + sb[7];
  float mean = S * (1.f / H_DIM);
  float var = Q * (1.f / H_DIM) - mean * mean;
  float inv = rsqrtf(var + 1e-5f);
  f4v g4 = *(const f4v*)(gamma + tid * 4);
  f4v b4 = *(const f4v*)(beta + tid * 4);
  f4v o;
  #pragma unroll
  for (int e = 0; e < 4; ++e) o[e] = (v[e] - mean) * inv * g4[e] + b4[e];
  *(f4v*)(p + tid * 4) = o;
}

// ---------------- host ----------------
extern "C" void kernel_launch(void* const* d_in, const int* in_sizes, int n_in,
                              void* d_out, int out_size, void* d_ws, size_t ws_size,
                              hipStream_t stream) {
  const float* x     = (const float*)d_in[0];
  const float* hxs   = (const float*)d_in[1];
  const float* masks = (const float*)d_in[2];
  const float* W_ih  = (const float*)d_in[3];
  const float* W_hh  = (const float*)d_in[4];
  const float* b_ih  = (const float*)d_in[5];
  const float* b_hh  = (const float*)d_in[6];
  const float* gamma = (const float*)d_in[7];
  const float* beta  = (const float*)d_in[8];
  float* y = (float*)d_out;                                 // [65536][1024]
  float* hlast = y + (size_t)T_STEPS * N_B * H_DIM;         // [512][1024]

  char* ws = (char*)d_ws;
  unsigned short* Wih_bf = (unsigned short*)ws;  ws += (size_t)G_DIM * D_IN * 2;       // 6.3 MB
  unsigned short* Whh_bf = (unsigned short*)ws;  ws += (size_t)G_DIM * H_DIM * 2;      // 6.3 MB
  unsigned short* xc_bf  = (unsigned short*)ws;  ws += (size_t)M_ALL * D_IN * 2;       // 134 MB
  unsigned short* xp_bf  = (unsigned short*)ws;  ws += (size_t)M_ALL * G_DIM * 2;      // 403 MB
  unsigned short* hbuf   = (unsigned short*)ws;  ws += (size_t)2 * N_B * H_DIM * 2;    // 2.1 MB
  int* reset             = (int*)ws;             ws += 512;

  cvt_bf16<<<1024, 256, 0, stream>>>(W_ih, Wih_bf, (long)G_DIM * D_IN / 4);
  cvt_bf16<<<1024, 256, 0, stream>>>(W_hh, Whh_bf, (long)G_DIM * H_DIM / 4);
  cvt_bf16<<<512, 256, 0, stream>>>(hxs, hbuf, (long)N_B * H_DIM / 4);   // hbuf[0] = bf16(h0)
  reset_kernel<<<128, 512, 0, stream>>>(masks, reset);
  cvt_bf16<<<4096, 256, 0, stream>>>(x, xc_bf, (long)M_ALL * D_IN / 4);

  dim3 gg(G_DIM / 128, M_ALL / 128);   // (24, 512) — one GEMM for all timesteps
  gemm_xp<<<gg, 256, 0, stream>>>(xc_bf, Wih_bf, b_ih, xp_bf);

  const size_t NH = (size_t)N_B * H_DIM;
  for (int t = 0; t < T_STEPS; ++t) {
    const unsigned short* hread = hbuf + (size_t)(t & 1) * NH;
    unsigned short* hwrite = hbuf + (size_t)((t & 1) ^ 1) * NH;
    gru_step6<<<256, 256, 0, stream>>>(Whh_bf, xp_bf, masks, reset, b_hh,
                                       hxs, hread, hwrite, y, hlast, t);
  }

  ln_kernel<<<T_STEPS * N_B, 256, 0, stream>>>(y, gamma, beta);
}

// Round 11
// 2483.466 us; speedup vs baseline: 2.5709x; 1.0378x over previous
//
#include <hip/hip_runtime.h>

// ---------------- problem constants ----------------
#define T_STEPS 128
#define N_B     512
#define D_IN    1024
#define H_DIM   1024
#define G_DIM   3072        // 3*H
#define M_ALL   (T_STEPS * N_B)   // 65536 rows

typedef short          s8v  __attribute__((ext_vector_type(8)));   // 8 bf16 (4 VGPR)
typedef float          f4v  __attribute__((ext_vector_type(4)));
typedef unsigned short u4v  __attribute__((ext_vector_type(4)));

__device__ __forceinline__ unsigned short f2bf(float f) {
  union { float f; unsigned u; } v; v.f = f;
  unsigned r = v.u + 0x7FFFu + ((v.u >> 16) & 1u);   // RNE
  return (unsigned short)(r >> 16);
}
__device__ __forceinline__ float bf2f(unsigned short h) {
  union { unsigned u; float f; } v; v.u = ((unsigned)h) << 16;
  return v.f;
}
__device__ __forceinline__ void async16(const void* g, void* l) {
  __builtin_amdgcn_global_load_lds(
      (const __attribute__((address_space(1))) unsigned*)g,
      (__attribute__((address_space(3))) unsigned*)l, 16, 0, 0);
}
__device__ __forceinline__ float sigmoidf_(float x) { return 1.f / (1.f + __expf(-x)); }
__device__ __forceinline__ float tanhf_(float x)    { return 1.f - 2.f / (1.f + __expf(2.f * x)); }

// ---------------- f32 -> bf16 conversion (vectorized, grid-stride) ----------------
__global__ void cvt_bf16(const float* __restrict__ in, unsigned short* __restrict__ out, long n4) {
  long i = (long)blockIdx.x * blockDim.x + threadIdx.x;
  long stride = (long)gridDim.x * blockDim.x;
  for (; i < n4; i += stride) {
    f4v v = *(const f4v*)(in + i * 4);
    u4v o;
    #pragma unroll
    for (int e = 0; e < 4; ++e) o[e] = f2bf(v[e]);
    *(u4v*)(out + i * 4) = o;
  }
}

// ---------------- reset[t] = (t==0) || any(m[t,:]==1.0) ----------------
__global__ void reset_kernel(const float* __restrict__ masks, int* __restrict__ reset) {
  const int t = blockIdx.x;
  __shared__ int flag;
  if (threadIdx.x == 0) flag = (t == 0) ? 1 : 0;
  __syncthreads();
  if (t > 0 && masks[(size_t)t * N_B + threadIdx.x] == 1.0f) flag = 1;  // benign same-value race
  __syncthreads();
  if (threadIdx.x == 0) reset[t] = flag;
}

// ---------------- xp GEMM (ALL timesteps), TRANSPOSED output + LDS swizzle ----------------
// C^T[g][m] = sum_k A[m][k]*B[g][k] + bias[g].  A: x bf16 [65536][1024], B: W_ih [3072][1024].
// T2 both-sides swizzle: staging source col-elems ((l&7)^srow)*8, ds_read byte ^ ((row&7)<<4).
// Epilogue: acc rows (l4*4+r) are consecutive -> 8B u4v stores into xpT[g][m] (16 stores vs 64).
__global__ __launch_bounds__(256) void gemm_xp(const unsigned short* __restrict__ A,
                                               const unsigned short* __restrict__ B,
                                               const float* __restrict__ bias,
                                               unsigned short* __restrict__ C) {
  const int m0 = blockIdx.y * 128, g0 = blockIdx.x * 128;
  const int tid = threadIdx.x, wv = tid >> 6, l = tid & 63;
  const int l15 = l & 15, l4 = l >> 4;
  const int wr = wv >> 1, wc = wv & 1;
  __shared__ unsigned short As[128 * 64], Bs[128 * 64];

  f4v zero4 = {0.f, 0.f, 0.f, 0.f};
  f4v acc[4][4];
  #pragma unroll
  for (int i = 0; i < 4; ++i)
    #pragma unroll
    for (int j = 0; j < 4; ++j) acc[i][j] = zero4;

  const int srow = l >> 3;                       // row within 8-row segment
  const int selem = ((l & 7) ^ srow) * 8;        // pre-swizzled source col (elements)
  const int swz_rd = (l15 & 7) << 4;             // read-side row-XOR (rr&7 == l15&7)

  for (int kt = 0; kt < 1024; kt += 64) {
    #pragma unroll
    for (int cc = 0; cc < 4; ++cc) {
      int s = wv * 4 + cc;
      int row = s * 8 + srow;
      async16(A + (size_t)(m0 + row) * 1024 + kt + selem, &As[s * 512]);
      async16(B + (size_t)(g0 + row) * 1024 + kt + selem, &Bs[s * 512]);
    }
    __syncthreads();
    #pragma unroll
    for (int ks = 0; ks < 2; ++ks) {
      s8v a[4], b[4];
      #pragma unroll
      for (int i = 0; i < 4; ++i) {
        int ra = wr * 64 + i * 16 + l15, rb = wc * 64 + i * 16 + l15;
        int cb = (ks * 64 + l4 * 16) ^ swz_rd;
        a[i] = *(const s8v*)((const char*)As + ra * 128 + cb);
        b[i] = *(const s8v*)((const char*)Bs + rb * 128 + cb);
      }
      #pragma unroll
      for (int i = 0; i < 4; ++i)
        #pragma unroll
        for (int j = 0; j < 4; ++j)
          acc[i][j] = __builtin_amdgcn_mfma_f32_16x16x32_bf16(a[i], b[j], acc[i][j], 0, 0, 0);
    }
    __syncthreads();
  }
  #pragma unroll
  for (int j = 0; j < 4; ++j) {
    int gcol = g0 + wc * 64 + j * 16 + l15;
    float bv = bias[gcol];
    #pragma unroll
    for (int i = 0; i < 4; ++i) {
      int mrow = m0 + wr * 64 + i * 16 + l4 * 4;
      u4v o;
      #pragma unroll
      for (int r = 0; r < 4; ++r) o[r] = f2bf(acc[i][j][r] + bv);
      *(u4v*)(C + (size_t)gcol * M_ALL + mrow) = o;    // transposed, 8B vector store
    }
  }
}

// ---------------- one GRU timestep, v7 ----------------
// Grid 256 (1/CU): jt = bid&31 (j0=jt*32), nt = bid>>5 (n0=nt*64). XCD=jt%8 -> W L2-resident
// across launches. Pipeline (exact-counted): P-loads (fast L2/L3: masks/bhh/h_prev-f32) FIRST,
// then S0,S1,S2 (10 VMEM each, builtin -> exact), then XP (3 builtin: xp^T gate operands ->
// 12KB LDS, HBM latency absorbed by kt3). Per-kt: s_waitcnt vmcnt(N) + raw s_barrier, N exact
// because everything younger than each S-target is builtin-counted. Gates read xp from LDS,
// h_prev from hf32 (8MB L3-hot side buffer; identical f32 values to y[t-1]).
__global__ __launch_bounds__(256) void gru_step7(
    const unsigned short* __restrict__ Whh,   // [3072][1024] bf16
    const unsigned short* __restrict__ xpT,   // [3072][65536] bf16 (+b_ih), transposed
    const float* __restrict__ masks,          // [T*N]
    const int* __restrict__ reset,            // [T]
    const float* __restrict__ bhh,            // [3072]
    const float* __restrict__ hxs,            // [512][1024] initial h (f32)
    const unsigned short* __restrict__ hread, // bf16 h_prev [512][1024]
    unsigned short* __restrict__ hwrite,      // bf16 h_new  [512][1024]
    const float* __restrict__ hf32r,          // f32 h_prev [512][1024]
    float* __restrict__ hf32w,                // f32 h_new  [512][1024]
    float* __restrict__ y,                    // [T*N][1024]
    float* __restrict__ hlast,                // [512][1024]
    int t) {
  const int bid = blockIdx.x;
  const int jt = bid & 31, nt = bid >> 5;
  const int j0 = jt * 32, n0 = nt * 64;
  const int tid = threadIdx.x, w = tid >> 6, l = tid & 63;
  const int l15 = l & 15, l4 = l >> 4;
  const int wn = w & 1, wj = w >> 1;          // wave -> (n-half of 32, j-half of 16)
  const size_t NH = (size_t)N_B * H_DIM;

  __shared__ unsigned short Hs[3][64 * 128];  // 3 x 16 KB (h slab, swizzled)
  __shared__ unsigned short Ws[3][96 * 128];  // 3 x 24 KB (W slab, swizzled)
  __shared__ unsigned short xpl[3][32][64];   // 12 KB xp gate operands (swizzled cols)

  const int lrow4 = l >> 4;                   // staging: lane -> row-within-4
  const int lcb = (l & 15) * 16;              // staging: lane -> 16B col slot
  const int swz_rd = (l15 & 7) << 4;          // read-side row-XOR

  const int jj = j0 + wj * 16 + l15;
  const int rst = reset[t];

  // ---- P: fast prefetches FIRST (L2/L3-hot; keeps later S-counts exact) ----
  bool zo[2];
  #pragma unroll
  for (int i = 0; i < 2; ++i) {
    float mv = masks[(size_t)t * N_B + n0 + wn * 32 + i * 16 + l15];
    zo[i] = rst && (mv == 0.0f);
  }
  const float* hsrc = (t == 0) ? hxs : hf32r;
  float hreg[2][4], mreg[2][4];
  #pragma unroll
  for (int i = 0; i < 2; ++i)
    #pragma unroll
    for (int r = 0; r < 4; ++r) {
      const int n = n0 + wn * 32 + i * 16 + l4 * 4 + r;
      hreg[i][r] = hsrc[(size_t)n * H_DIM + jj];
      mreg[i][r] = masks[(size_t)t * N_B + n];
    }
  const float br = bhh[jj];
  const float bz = bhh[H_DIM + jj];
  const float bn = bhh[2 * H_DIM + jj];

  f4v zero4 = {0.f, 0.f, 0.f, 0.f};
  s8v zer8 = {0, 0, 0, 0, 0, 0, 0, 0};
  f4v acc[2][3];
  #pragma unroll
  for (int i = 0; i < 2; ++i)
    #pragma unroll
    for (int g3 = 0; g3 < 3; ++g3) acc[i][g3] = zero4;

  // ---- staging: 10 builtin VMEM per call (wave-uniform dest, pre-swizzled source) ----
  auto stage = [&](int buf, int kt) {
    #pragma unroll
    for (int q = 0; q < 4; ++q) {
      int rb = w * 16 + q * 4;
      int row = rb + lrow4;                                   // 0..63
      int cb = lcb ^ ((row & 7) << 4);                        // byte in 256B row
      async16(hread + (size_t)(n0 + row) * H_DIM + kt * 128 + (cb >> 1), &Hs[buf][rb * 128]);
    }
    #pragma unroll
    for (int q = 0; q < 6; ++q) {
      int rb = w * 24 + q * 4;
      int row = rb + lrow4;                                   // 0..95
      int gate = row >> 5, jjl = row & 31;
      int cb = lcb ^ ((row & 7) << 4);
      async16(Whh + ((size_t)gate * H_DIM + j0 + jjl) * H_DIM + kt * 128 + (cb >> 1),
              &Ws[buf][rb * 128]);                            // L2-resident per XCD
    }
  };

  stage(0, 0); stage(1, 1); stage(2, 2);       // 30 VMEM: all three buffers prestaged

  // ---- XP: xp^T gate operands -> LDS (3 builtin VMEM/wave; HBM, lands by kt3) ----
  {
    const int jl = w * 8 + (l >> 3);                          // wave w covers jl w*8..w*8+7
    const int nelem = ((l & 7) ^ (l >> 3)) * 8;               // pre-swizzled n-offset (elems)
    #pragma unroll
    for (int g3 = 0; g3 < 3; ++g3)
      async16(xpT + (size_t)(g3 * H_DIM + j0 + jl) * M_ALL + (size_t)t * N_B + n0 + nelem,
              &xpl[g3][w * 8][0]);
  }

  // ---- kt pipeline: exact counted vmcnt + raw s_barrier ----
  // after-target counts: kt0: S1,S2,XP=23 | kt1: S2,XP=13 | kt2: XP,S3=13 | kt3+: 10 | kt7: 0
#define KT_BODY(KT, VM, DO_STAGE)                                              \
  {                                                                            \
    asm volatile("s_waitcnt vmcnt(" #VM ")" ::: "memory");                     \
    __builtin_amdgcn_s_barrier();                                              \
    __builtin_amdgcn_sched_barrier(0);                                         \
    if (DO_STAGE) stage((KT + 2) % 3, KT + 2);                                 \
    const char* hb = (const char*)&Hs[KT % 3][0];                              \
    const char* wb = (const char*)&Ws[KT % 3][0];                              \
    _Pragma("unroll")                                                          \
    for (int ks = 0; ks < 4; ++ks) {                                           \
      const int kbb = (ks * 64 + l4 * 16) ^ swz_rd;                            \
      s8v a[2], b[3];                                                          \
      _Pragma("unroll")                                                        \
      for (int i = 0; i < 2; ++i) {                                            \
        a[i] = *(const s8v*)(hb + (wn * 32 + i * 16 + l15) * 256 + kbb);       \
        if (zo[i]) a[i] = zer8;                                                \
      }                                                                        \
      _Pragma("unroll")                                                        \
      for (int g3 = 0; g3 < 3; ++g3)                                           \
        b[g3] = *(const s8v*)(wb + (g3 * 32 + wj * 16 + l15) * 256 + kbb);     \
      _Pragma("unroll")                                                        \
      for (int i = 0; i < 2; ++i)                                              \
        _Pragma("unroll")                                                      \
        for (int g3 = 0; g3 < 3; ++g3)                                         \
          acc[i][g3] = __builtin_amdgcn_mfma_f32_16x16x32_bf16(a[i], b[g3],    \
                                                              acc[i][g3], 0, 0, 0); \
    }                                                                          \
  }

  KT_BODY(0, 23, false)
  KT_BODY(1, 13, true)
  KT_BODY(2, 13, true)
  KT_BODY(3, 10, true)
  KT_BODY(4, 10, true)
  KT_BODY(5, 10, true)
  KT_BODY(6, 10, false)
  KT_BODY(7, 0,  false)
#undef KT_BODY

  // ---- gates: xp from LDS (all waves' XP landed before kt7's barrier), h_prev from regs ----
  #pragma unroll
  for (int i = 0; i < 2; ++i) {
    #pragma unroll
    for (int r = 0; r < 4; ++r) {
      const int n = n0 + wn * 32 + i * 16 + l4 * 4 + r;
      const int nl = wn * 32 + i * 16 + l4 * 4 + r;           // n-local 0..63
      const int jl = wj * 16 + l15;                           // j-local 0..31
      float hprev = hreg[i][r];
      if (rst && mreg[i][r] == 0.0f) hprev = 0.0f;
      const float hr = acc[i][0][r] + br;
      const float hz = acc[i][1][r] + bz;
      const float hn = acc[i][2][r] + bn;
      const char* xb = (const char*)&xpl[0][0][0];
      const int nb = (nl * 2) ^ ((jl & 7) << 4);              // swizzled byte in 128B col
      const float xr = bf2f(*(const unsigned short*)(xb + 0 * 4096 + jl * 128 + nb));
      const float xz = bf2f(*(const unsigned short*)(xb + 1 * 4096 + jl * 128 + nb));
      const float xn = bf2f(*(const unsigned short*)(xb + 2 * 4096 + jl * 128 + nb));
      const float rg = sigmoidf_(xr + hr);
      const float zg = sigmoidf_(xz + hz);
      const float ng = tanhf_(xn + rg * hn);
      const float hnew = (1.f - zg) * ng + zg * hprev;
      const size_t gidx = (size_t)n * H_DIM + jj;
      y[(size_t)t * NH + gidx] = hnew;
      hwrite[gidx] = f2bf(hnew);
      hf32w[gidx] = hnew;
      if (t == T_STEPS - 1) hlast[gidx] = hnew;
    }
  }
}

// ---------------- final LayerNorm over y rows (in place) ----------------
__global__ __launch_bounds__(256) void ln_kernel(float* __restrict__ y,
                                                 const float* __restrict__ gamma,
                                                 const float* __restrict__ beta) {
  const size_t row = blockIdx.x;
  float* p = y + row * (size_t)H_DIM;
  const int tid = threadIdx.x;
  f4v v = *(const f4v*)(p + tid * 4);
  float s = v[0] + v[1] + v[2] + v[3];
  float q = v[0] * v[0] + v[1] * v[1] + v[2] * v[2] + v[3] * v[3];
  #pragma unroll
  for (int off = 32; off > 0; off >>= 1) {
    s += __shfl_down(s, off);
    q += __shfl_down(q, off);
  }
  __shared__ float sb[8];
  const int wid = tid >> 6, lid = tid & 63;
  if (lid == 0) { sb[wid] = s; sb[4 + wid] = q; }
  __syncthreads();
  float S = sb[0] + sb[1] + sb[2] + sb[3];
  float Q = sb[4] + sb[5] + sb[6] + sb[7];
  float mean = S * (1.f / H_DIM);
  float var = Q * (1.f / H_DIM) - mean * mean;
  float inv = rsqrtf(var + 1e-5f);
  f4v g4 = *(const f4v*)(gamma + tid * 4);
  f4v b4 = *(const f4v*)(beta + tid * 4);
  f4v o;
  #pragma unroll
  for (int e = 0; e < 4; ++e) o[e] = (v[e] - mean) * inv * g4[e] + b4[e];
  *(f4v*)(p + tid * 4) = o;
}

// ---------------- host ----------------
extern "C" void kernel_launch(void* const* d_in, const int* in_sizes, int n_in,
                              void* d_out, int out_size, void* d_ws, size_t ws_size,
                              hipStream_t stream) {
  const float* x     = (const float*)d_in[0];
  const float* hxs   = (const float*)d_in[1];
  const float* masks = (const float*)d_in[2];
  const float* W_ih  = (const float*)d_in[3];
  const float* W_hh  = (const float*)d_in[4];
  const float* b_ih  = (const float*)d_in[5];
  const float* b_hh  = (const float*)d_in[6];
  const float* gamma = (const float*)d_in[7];
  const float* beta  = (const float*)d_in[8];
  float* y = (float*)d_out;                                 // [65536][1024]
  float* hlast = y + (size_t)T_STEPS * N_B * H_DIM;         // [512][1024]

  char* ws = (char*)d_ws;
  unsigned short* Wih_bf = (unsigned short*)ws;  ws += (size_t)G_DIM * D_IN * 2;       // 6.3 MB
  unsigned short* Whh_bf = (unsigned short*)ws;  ws += (size_t)G_DIM * H_DIM * 2;      // 6.3 MB
  unsigned short* xc_bf  = (unsigned short*)ws;  ws += (size_t)M_ALL * D_IN * 2;       // 134 MB
  unsigned short* xpT_bf = (unsigned short*)ws;  ws += (size_t)G_DIM * M_ALL * 2;      // 403 MB
  unsigned short* hbuf   = (unsigned short*)ws;  ws += (size_t)2 * N_B * H_DIM * 2;    // 2.1 MB
  float* hf32            = (float*)ws;           ws += (size_t)2 * N_B * H_DIM * 4;    // 4.2 MB
  int* reset             = (int*)ws;             ws += 512;

  cvt_bf16<<<1024, 256, 0, stream>>>(W_ih, Wih_bf, (long)G_DIM * D_IN / 4);
  cvt_bf16<<<1024, 256, 0, stream>>>(W_hh, Whh_bf, (long)G_DIM * H_DIM / 4);
  cvt_bf16<<<512, 256, 0, stream>>>(hxs, hbuf, (long)N_B * H_DIM / 4);   // hbuf[0] = bf16(h0)
  reset_kernel<<<128, 512, 0, stream>>>(masks, reset);
  cvt_bf16<<<4096, 256, 0, stream>>>(x, xc_bf, (long)M_ALL * D_IN / 4);

  dim3 gg(G_DIM / 128, M_ALL / 128);   // (24, 512) — one GEMM for all timesteps
  gemm_xp<<<gg, 256, 0, stream>>>(xc_bf, Wih_bf, b_ih, xpT_bf);

  const size_t NH = (size_t)N_B * H_DIM;
  for (int t = 0; t < T_STEPS; ++t) {
    const unsigned short* hread = hbuf + (size_t)(t & 1) * NH;
    unsigned short* hwrite = hbuf + (size_t)((t & 1) ^ 1) * NH;
    const float* hf32r = hf32 + (size_t)(t & 1) * NH;
    float* hf32w = hf32 + (size_t)((t & 1) ^ 1) * NH;
    gru_step7<<<256, 256, 0, stream>>>(Whh_bf, xpT_bf, masks, reset, b_hh,
                                       hxs, hread, hwrite, hf32r, hf32w, y, hlast, t);
  }

  ln_kernel<<<T_STEPS * N_B, 256, 0, stream>>>(y, gamma, beta);
}